// Round 12
// baseline (181.213 us; speedup 1.0000x reference)
//
#include <hip/hip_runtime.h>
#include <cstddef>

#define NB 8
#define NT 2048
#define NE 256
#define NH 4
#define ND 64
#define NP 8

typedef short bf16x8 __attribute__((ext_vector_type(8)));
typedef float f32x4 __attribute__((ext_vector_type(4)));
typedef float f32x16 __attribute__((ext_vector_type(16)));

__device__ __forceinline__ unsigned short f2bf(float f) {
  unsigned u = __builtin_bit_cast(unsigned, f);
  u += 0x7fffu + ((u >> 16) & 1u);          // RNE
  return (unsigned short)(u >> 16);
}
__device__ __forceinline__ float bf2f(unsigned short h) {
  unsigned u = ((unsigned)h) << 16;
  return __builtin_bit_cast(float, u);
}
// packed hi/lo split of a float pair (integer-only)
__device__ __forceinline__ void split2(float a, float b, unsigned& hi, unsigned& lo) {
  const unsigned short ha = f2bf(a), hb = f2bf(b);
  hi = (unsigned)ha | ((unsigned)hb << 16);
  const unsigned short la = f2bf(a - bf2f(ha));
  const unsigned short lb = f2bf(b - bf2f(hb));
  lo = (unsigned)la | ((unsigned)lb << 16);
}
__device__ __forceinline__ void gld16(const void* g, void* l) {
  __builtin_amdgcn_global_load_lds((const __attribute__((address_space(1))) unsigned*)g,
                                   (__attribute__((address_space(3))) unsigned*)l, 16, 0, 0);
}

// q-prescale: 1/8 (attn scale) * log2(e) (exp2 domain for softmax)
#define QSC 0.180336880111120419f

// ---------------- setup1: u = w_bd@w_o ; uv_h ; consts (1 block) -----------------------
__global__ __launch_bounds__(256) void setup1_kernel(
    const float* __restrict__ w_o, const float* __restrict__ b_o,
    const float* __restrict__ w_bd, const float* __restrict__ b_bd,
    const float* __restrict__ w_v, const float* __restrict__ b_v,
    float* __restrict__ uvbuf, float* __restrict__ consts)
{
  __shared__ float wbd_s[NE];
  __shared__ float u_s[NE];
  const int tid = threadIdx.x;
  wbd_s[tid] = w_bd[tid];
  __syncthreads();
  float a = 0.f;
  for (int j = 0; j < NE; ++j) a = fmaf(wbd_s[j], w_o[j * NE + tid], a);
  u_s[tid] = a;
  __syncthreads();
  #pragma unroll
  for (int hh = 0; hh < NH; ++hh) {
    float a2 = 0.f;
    for (int d = 0; d < ND; ++d)
      a2 = fmaf(u_s[hh * ND + d], w_v[(size_t)(hh * ND + d) * NE + tid], a2);
    uvbuf[hh * NE + tid] = a2;
  }
  if (tid == 0) {
    float cc = 0.f;
    for (int j = 0; j < NE; ++j) cc = fmaf(wbd_s[j], b_o[j], cc);
    consts[0] = cc + b_bd[0];
  }
  if (tid >= 8 && tid < 12) {
    const int hh = tid - 8;
    float cv = 0.f;
    for (int d = 0; d < ND; ++d) cv = fmaf(u_s[hh * ND + d], b_v[hh * ND + d], cv);
    consts[1 + hh] = cv;
  }
}

// ---------------- setup2: build fused weight rows [832][256] + biases, split hi/lo -----
// rows 0..255 = w_in ; 256..511 = QSC*(w_q@w_in) ; 512..767 = w_k@w_in ;
// 768..771 = uv@w_in ; 772..831 = 0. block 832: zero psum.
__global__ __launch_bounds__(256) void setup2_kernel(
    const float* __restrict__ w_in, const float* __restrict__ w_q,
    const float* __restrict__ w_k, const float* __restrict__ b_in,
    const float* __restrict__ b_q, const float* __restrict__ b_k,
    const float* __restrict__ uvbuf, const float* __restrict__ consts,
    unsigned short* __restrict__ wfhi, unsigned short* __restrict__ wflo,
    float* __restrict__ bias_f, float* __restrict__ psum)
{
  __shared__ float row_s[256];
  __shared__ float red[256];
  const int b = blockIdx.x, tid = threadIdx.x;
  if (b == 832) {
    for (int i = tid; i < NB * NP * NE; i += 256) psum[i] = 0.f;
    return;
  }
  float v = 0.f, bias = 0.f;
  if (b < 256) {
    v = w_in[(size_t)b * 256 + tid];
    bias = b_in[b];
  } else if (b < 772) {
    const float* wrow = (b < 512) ? (w_q + (size_t)(b - 256) * 256)
                      : (b < 768) ? (w_k + (size_t)(b - 512) * 256)
                                  : (uvbuf + (size_t)(b - 768) * 256);
    row_s[tid] = wrow[tid];
    __syncthreads();
    float acc = 0.f;
    for (int e = 0; e < 256; ++e) acc = fmaf(row_s[e], w_in[(size_t)e * 256 + tid], acc);
    v = acc;
    red[tid] = row_s[tid] * b_in[tid];
    __syncthreads();
    for (int off = 128; off > 0; off >>= 1) {
      if (tid < off) red[tid] += red[tid + off];
      __syncthreads();
    }
    bias = red[0] + ((b < 512) ? b_q[b - 256] : (b < 768) ? b_k[b - 512]
                                              : consts[1 + (b - 768)]);
    if (b < 512) { v *= QSC; bias *= QSC; }
  }
  const unsigned short hb = f2bf(v);
  wfhi[(size_t)b * 256 + tid] = hb;
  wflo[(size_t)b * 256 + tid] = f2bf(v - bf2f(hb));
  if (tid == 0) bias_f[b] = bias;
}

// ---------------- xgemm: [h | q*QSC | k | vu] = x @ Wf^T + bias_f ----------------------
// BM=128 BN=64 BK=32; 256 thr / 4 waves; grid 1664 XCD-swizzled; A = x f32, in-reg split.
__global__ __launch_bounds__(256) void xgemm_kernel(
    const float* __restrict__ x,
    const unsigned short* __restrict__ wfhi, const unsigned short* __restrict__ wflo,
    const float* __restrict__ bias_f,
    unsigned short* __restrict__ hhi,
    unsigned short* __restrict__ Qhi, unsigned short* __restrict__ Qlo,
    unsigned short* __restrict__ Khi, unsigned short* __restrict__ Klo,
    float* __restrict__ vubuf)
{
  __shared__ __align__(16) char sm[2][24576];
  const int tid = threadIdx.x;
  const int wave = tid >> 6, lane = tid & 63;
  const int lr = lane & 15, lg = lane >> 4;
  const int wm = wave >> 1, wn = wave & 1;
  const int bid = blockIdx.x;
  const int idx = bid >> 3;                     // 0..207
  const int m0 = ((bid & 7) * 16 + idx / 13) * 128;
  const int n0 = (idx % 13) * 64;

  const float* aSrc[4];
  #pragma unroll
  for (int c = 0; c < 4; ++c) {
    const int L = c * 4096 + tid * 16;
    const int row = L >> 7, w = (L >> 4) & 7;
    aSrc[c] = x + (size_t)(m0 + row) * 256 + (w ^ (row & 7)) * 4;
  }
  const unsigned short* wSrc[2];
  #pragma unroll
  for (int c = 0; c < 2; ++c) {
    const int L = c * 4096 + tid * 16;
    const int half = (L >> 12) & 1;
    const int Lh = L & 4095;
    const int col = Lh >> 6, w = (Lh >> 4) & 3;
    wSrc[c] = (half ? wflo : wfhi) + (size_t)(n0 + col) * 256 + (w ^ ((col >> 1) & 3)) * 8;
  }
  int aoff[4][2], woff[2];
  #pragma unroll
  for (int s = 0; s < 4; ++s) {
    const int row = wm * 64 + s * 16 + lr;
    const int b0 = row * 128 + lg * 32;
    const int f = (row & 7) << 4;
    aoff[s][0] = b0 ^ f;
    aoff[s][1] = (b0 + 16) ^ f;
  }
  #pragma unroll
  for (int ns = 0; ns < 2; ++ns) {
    const int col = wn * 32 + ns * 16 + lr;
    woff[ns] = (col * 64 + lg * 16) ^ (((col >> 1) & 3) << 4);
  }

  f32x4 acc[4][2];
  #pragma unroll
  for (int s = 0; s < 4; ++s)
    #pragma unroll
    for (int ns = 0; ns < 2; ++ns) acc[s][ns] = (f32x4){0.f, 0.f, 0.f, 0.f};

  {
    char* lb = sm[0];
    #pragma unroll
    for (int c = 0; c < 4; ++c) gld16(aSrc[c], lb + c * 4096 + wave * 1024);
    #pragma unroll
    for (int c = 0; c < 2; ++c) gld16(wSrc[c], lb + 16384 + c * 4096 + wave * 1024);
  }

  for (int kt = 0; kt < 8; ++kt) {
    __syncthreads();
    if (kt < 7) {
      char* nb = sm[(kt + 1) & 1];
      #pragma unroll
      for (int c = 0; c < 4; ++c) gld16(aSrc[c] + (kt + 1) * 32, nb + c * 4096 + wave * 1024);
      #pragma unroll
      for (int c = 0; c < 2; ++c) gld16(wSrc[c] + (kt + 1) * 32, nb + 16384 + c * 4096 + wave * 1024);
    }
    const char* lb = sm[kt & 1];
    bf16x8 ah[4], al[4], wh[2], wl[2];
    #pragma unroll
    for (int s = 0; s < 4; ++s) {
      const f32x4 p0 = *(const f32x4*)(lb + aoff[s][0]);
      const f32x4 p1 = *(const f32x4*)(lb + aoff[s][1]);
      unsigned h0, h1, h2, h3, l0, l1, l2, l3;
      split2(p0[0], p0[1], h0, l0);
      split2(p0[2], p0[3], h1, l1);
      split2(p1[0], p1[1], h2, l2);
      split2(p1[2], p1[3], h3, l3);
      const uint4 hu = make_uint4(h0, h1, h2, h3);
      const uint4 lu = make_uint4(l0, l1, l2, l3);
      ah[s] = __builtin_bit_cast(bf16x8, hu);
      al[s] = __builtin_bit_cast(bf16x8, lu);
    }
    #pragma unroll
    for (int ns = 0; ns < 2; ++ns) {
      wh[ns] = *(const bf16x8*)(lb + 16384 + woff[ns]);
      wl[ns] = *(const bf16x8*)(lb + 20480 + woff[ns]);
    }
    #pragma unroll
    for (int s = 0; s < 4; ++s)
      #pragma unroll
      for (int ns = 0; ns < 2; ++ns) {
        acc[s][ns] = __builtin_amdgcn_mfma_f32_16x16x32_bf16(ah[s], wh[ns], acc[s][ns], 0, 0, 0);
        acc[s][ns] = __builtin_amdgcn_mfma_f32_16x16x32_bf16(ah[s], wl[ns], acc[s][ns], 0, 0, 0);
        acc[s][ns] = __builtin_amdgcn_mfma_f32_16x16x32_bf16(al[s], wh[ns], acc[s][ns], 0, 0, 0);
      }
  }
  #pragma unroll
  for (int s = 0; s < 4; ++s)
    #pragma unroll
    for (int ns = 0; ns < 2; ++ns)
      #pragma unroll
      for (int reg = 0; reg < 4; ++reg) {
        const int row = m0 + wm * 64 + s * 16 + lg * 4 + reg;
        const int col = n0 + wn * 32 + ns * 16 + lr;
        const float v = acc[s][ns][reg] + bias_f[col];
        const int b = row >> 11, t = row & 2047;
        if (col < 256) {
          hhi[(size_t)row * 256 + col] = f2bf(v);
        } else if (col < 768) {
          const int c = (col - 256) & 255;
          const int head = c >> 6, d = c & 63;
          const size_t i2 = (((size_t)(b * NH + head)) * NT + t) * ND + d;
          const unsigned short hb = f2bf(v);
          const unsigned short lb2 = f2bf(v - bf2f(hb));
          if (col < 512) { Qhi[i2] = hb; Qlo[i2] = lb2; }
          else           { Khi[i2] = hb; Klo[i2] = lb2; }
        } else if (col < 772) {
          vubuf[((size_t)(b * NH + (col - 768))) * NT + t] = v;
        }
      }
}

// ---------------- attention v9: 32x32x16 MFMA, stage-once, wave-staggered --------------
// split-K x8: 2048 blocks; block = 256 q x 256 k (4 tiles staged upfront, 1 barrier).
// 512 thr / 8 waves; wave = 32 q-rows via one 32x32 column stripe. exp2-domain softmax.
// A/B frag: row=lane&31, k=8*(lane>>5)+i. D: col=lane&31, row=(reg&3)+8*(reg>>2)+4*(lane>>5).
__global__ __launch_bounds__(512, 4) void attn_kernel9(
    const unsigned short* __restrict__ qhi, const unsigned short* __restrict__ qlo,
    const unsigned short* __restrict__ khi, const unsigned short* __restrict__ klo,
    const float* __restrict__ vu, float2* __restrict__ part2)
{
  __shared__ __align__(16) char kbuf[4][16384];   // 4 tiles x [hi 8KB | lo 8KB], swizzled
  __shared__ float vu_s[256];
  const int tid = threadIdx.x;
  const int wave = tid >> 6, lane = tid & 63;
  const int lk = lane & 31;          // A q-row / B k-row / D col
  const int lh = lane >> 5;          // k-half selector; D row +4
  // XCD-aware: bid&7 -> XCD; each XCD covers 4 contiguous bh
  const int bid = blockIdx.x;                     // 0..2047
  const int idx = bid >> 3;                       // 0..255
  const int bh = (bid & 7) * 4 + (idx >> 6);
  const int rem = idx & 63;
  const int qt = rem >> 3, kh = rem & 7;
  const size_t base = (size_t)bh * NT * ND;
  const int qrow0 = qt * 256 + wave * 32;
  const int krow0 = kh * 256;

  if (tid < 256) vu_s[tid] = vu[(size_t)bh * NT + krow0 + tid];

  // Q fragments: [d-slice 4][hi/lo]; 8 bf16 at q[qrow0+lk][ds*16 + lh*8 ...]
  bf16x8 qf[4][2];
  #pragma unroll
  for (int ds = 0; ds < 4; ++ds) {
    const size_t off = base + (size_t)(qrow0 + lk) * ND + ds * 16 + lh * 8;
    qf[ds][0] = *(const bf16x8*)(qhi + off);
    qf[ds][1] = *(const bf16x8*)(qlo + off);
  }

  // staging (same pre-swizzled involution as before; LDS dest linear per lane)
  const int so = (tid * 16) ^ (((tid >> 3) & 7) << 4);
  // read offsets: row r = sub*32+lk (128B rows), byte col (32*ds + 16*lh) ^ ((lk&7)<<4)
  int ro[2][4];
  #pragma unroll
  for (int sub = 0; sub < 2; ++sub)
    #pragma unroll
    for (int ds = 0; ds < 4; ++ds)
      ro[sub][ds] = (sub * 32 + lk) * 128 + ((32 * ds + 16 * lh) ^ ((lk & 7) << 4));

  const char* srcH = (const char*)(khi + base + (size_t)krow0 * ND);
  const char* srcL = (const char*)(klo + base + (size_t)krow0 * ND);
  #pragma unroll
  for (int t = 0; t < 4; ++t) {
    gld16(srcH + t * 8192 + so, &kbuf[t][wave * 1024]);
    gld16(srcL + t * 8192 + so, &kbuf[t][8192 + wave * 1024]);
  }
  __syncthreads();                                // only barrier

  float l[16], sv[16];
  #pragma unroll
  for (int i = 0; i < 16; ++i) { l[i] = 0.f; sv[i] = 0.f; }
  f32x16 Z;
  #pragma unroll
  for (int i = 0; i < 16; ++i) Z[i] = 0.f;

  #pragma unroll
  for (int it = 0; it < 4; ++it) {
    const int kt = (it + wave) & 3;               // wave-staggered tile order
    const char* kb = (const char*)kbuf[kt];
    #pragma unroll
    for (int sub = 0; sub < 2; ++sub) {
      const float vuv = vu_s[kt * 64 + sub * 32 + lk];
      f32x16 acc;
      __builtin_amdgcn_s_setprio(1);
      {
        const bf16x8 kh0 = *(const bf16x8*)(kb + ro[sub][0]);
        const bf16x8 kl0 = *(const bf16x8*)(kb + 8192 + ro[sub][0]);
        acc = __builtin_amdgcn_mfma_f32_32x32x16_bf16(qf[0][0], kh0, Z, 0, 0, 0);
        acc = __builtin_amdgcn_mfma_f32_32x32x16_bf16(qf[0][0], kl0, acc, 0, 0, 0);
        acc = __builtin_amdgcn_mfma_f32_32x32x16_bf16(qf[0][1], kh0, acc, 0, 0, 0);
      }
      {
        const bf16x8 kh1 = *(const bf16x8*)(kb + ro[sub][1]);
        const bf16x8 kl1 = *(const bf16x8*)(kb + 8192 + ro[sub][1]);
        acc = __builtin_amdgcn_mfma_f32_32x32x16_bf16(qf[1][0], kh1, acc, 0, 0, 0);
        acc = __builtin_amdgcn_mfma_f32_32x32x16_bf16(qf[1][0], kl1, acc, 0, 0, 0);
        acc = __builtin_amdgcn_mfma_f32_32x32x16_bf16(qf[1][1], kh1, acc, 0, 0, 0);
      }
      {
        const bf16x8 kh2 = *(const bf16x8*)(kb + ro[sub][2]);
        const bf16x8 kl2 = *(const bf16x8*)(kb + 8192 + ro[sub][2]);
        acc = __builtin_amdgcn_mfma_f32_32x32x16_bf16(qf[2][0], kh2, acc, 0, 0, 0);
        acc = __builtin_amdgcn_mfma_f32_32x32x16_bf16(qf[2][0], kl2, acc, 0, 0, 0);
        acc = __builtin_amdgcn_mfma_f32_32x32x16_bf16(qf[2][1], kh2, acc, 0, 0, 0);
      }
      {
        const bf16x8 kh3 = *(const bf16x8*)(kb + ro[sub][3]);
        const bf16x8 kl3 = *(const bf16x8*)(kb + 8192 + ro[sub][3]);
        acc = __builtin_amdgcn_mfma_f32_32x32x16_bf16(qf[3][0], kh3, acc, 0, 0, 0);
        acc = __builtin_amdgcn_mfma_f32_32x32x16_bf16(qf[3][0], kl3, acc, 0, 0, 0);
        acc = __builtin_amdgcn_mfma_f32_32x32x16_bf16(qf[3][1], kh3, acc, 0, 0, 0);
      }
      __builtin_amdgcn_s_setprio(0);
      // exp2-domain softmax accumulation
      #pragma unroll
      for (int reg = 0; reg < 16; ++reg) {
        const float e = __builtin_amdgcn_exp2f(acc[reg]);
        l[reg] += e;
        sv[reg] = fmaf(e, vuv, sv[reg]);
      }
    }
  }
  // reduce l/sv across the 32-lane column group
  #pragma unroll
  for (int reg = 0; reg < 16; ++reg) {
    #pragma unroll
    for (int off = 1; off < 32; off <<= 1) {
      l[reg]  += __shfl_xor(l[reg],  off);
      sv[reg] += __shfl_xor(sv[reg], off);
    }
  }
  if (lk == 0) {
    #pragma unroll
    for (int reg = 0; reg < 16; ++reg) {
      const int row = qrow0 + (reg & 3) + 8 * (reg >> 2) + 4 * lh;
      part2[(((size_t)bh * NT + row) << 3) + kh] = make_float2(l[reg], sv[reg]);
    }
  }
}

// ---------------- combine: reduce split-K x8 partials -> bs = sigmoid(logit) -----------
__global__ __launch_bounds__(256) void combine_kernel(
    const float4* __restrict__ part4, const float* __restrict__ consts,
    float* __restrict__ bs)
{
  const int gid = blockIdx.x * 256 + threadIdx.x;    // 0..16383
  const int b = gid >> 11, t = gid & 2047;
  float logit = consts[0];
  #pragma unroll
  for (int hh = 0; hh < NH; ++hh) {
    const size_t p0 = ((size_t)((b * NH + hh) * NT) + t) * 4;   // 4 float4 = 8 {l,sv}
    float lsum = 0.f, ssum = 0.f;
    #pragma unroll
    for (int q = 0; q < 4; ++q) {
      const float4 p = part4[p0 + q];
      lsum += p.x + p.z;
      ssum += p.y + p.w;
    }
    logit += ssum / lsum;
  }
  bs[gid] = 1.f / (1.f + expf(-logit));
}

// ---------------- boundary: cumsum bs, pid, counts (one block per batch) ---------------
__global__ __launch_bounds__(256) void boundary_kernel(
    const float* __restrict__ bs, int* __restrict__ pid, int* __restrict__ counts)
{
  const int b = blockIdx.x, tid = threadIdx.x;
  __shared__ float partial[256];
  __shared__ int cnt_s[8];
  float v[8];
  float run = 0.f;
  const float4 b0 = *(const float4*)(bs + b * NT + tid * 8);
  const float4 b1 = *(const float4*)(bs + b * NT + tid * 8 + 4);
  const float bv[8] = {b0.x, b0.y, b0.z, b0.w, b1.x, b1.y, b1.z, b1.w};
  #pragma unroll
  for (int i = 0; i < 8; ++i) { run += bv[i]; v[i] = run; }
  float x = run;
  partial[tid] = x;
  __syncthreads();
  for (int off = 1; off < 256; off <<= 1) {
    const float y = (tid >= off) ? partial[tid - off] : 0.f;
    __syncthreads();
    x += y;
    partial[tid] = x;
    __syncthreads();
  }
  const float total = partial[255];
  if (tid < 8) cnt_s[tid] = 0;
  __syncthreads();
  const float denom = fmaxf(total, 1e-6f);
  const float excl = x - run;
  #pragma unroll
  for (int i = 0; i < 8; ++i) {
    const float norm = (excl + v[i]) / denom;
    int pp = (int)(norm * 8.f);
    pp = pp > 7 ? 7 : pp;
    pid[b * NT + tid * 8 + i] = pp;
    atomicAdd(&cnt_s[pp], 1);
  }
  __syncthreads();
  if (tid < 8) counts[b * 8 + tid] = cnt_s[tid];
}

// ---------------- pool hhi into patch sums (branchless 8-way select) -------------------
__global__ __launch_bounds__(256) void pool_kernel(
    const unsigned short* __restrict__ hhi, const int* __restrict__ pid,
    float* __restrict__ psum)
{
  const int b = blockIdx.x >> 4, chunk = blockIdx.x & 15;
  const int tid = threadIdx.x;
  __shared__ int pid_s[128];
  const int t0 = chunk * 128;
  if (tid < 128) pid_s[tid] = pid[b * NT + t0 + tid];
  __syncthreads();
  float acc[8] = {};
  for (int tok = 0; tok < 128; ++tok) {
    const float val = bf2f(hhi[((size_t)b * NT + t0 + tok) * NE + tid]);
    const int p = pid_s[tok];
    #pragma unroll
    for (int pp = 0; pp < 8; ++pp) acc[pp] += (p == pp) ? val : 0.f;
  }
  #pragma unroll
  for (int pp = 0; pp < 8; ++pp)
    atomicAdd(&psum[((size_t)b * NP + pp) * NE + tid], acc[pp]);
}

// ---------------- final: out = (psum/count) @ w_pr^T + b_pr ---------------------------
__global__ __launch_bounds__(256) void final_kernel(
    const float* __restrict__ psum, const int* __restrict__ counts,
    const float* __restrict__ w_pr, const float* __restrict__ b_pr, float* __restrict__ out)
{
  const int bp = blockIdx.x;
  const int tid = threadIdx.x;
  __shared__ float pe[NE];
  const float cnt = fmaxf((float)counts[bp], 1.f);
  pe[tid] = psum[(size_t)bp * NE + tid] / cnt;
  __syncthreads();
  float acc = 0.f;
  for (int e = 0; e < NE; ++e) acc = fmaf(pe[e], w_pr[(size_t)tid * NE + e], acc);
  out[(size_t)bp * NE + tid] = acc + b_pr[tid];
}

extern "C" void kernel_launch(void* const* d_in, const int* in_sizes, int n_in,
                              void* d_out, int out_size, void* d_ws, size_t ws_size,
                              hipStream_t stream) {
  (void)in_sizes; (void)n_in; (void)out_size; (void)ws_size;
  const float* x    = (const float*)d_in[0];
  const float* w_in = (const float*)d_in[1];
  const float* b_in = (const float*)d_in[2];
  const float* w_q  = (const float*)d_in[3];
  const float* b_q  = (const float*)d_in[4];
  const float* w_k  = (const float*)d_in[5];
  const float* b_k  = (const float*)d_in[6];
  const float* w_v  = (const float*)d_in[7];
  const float* b_v  = (const float*)d_in[8];
  const float* w_o  = (const float*)d_in[9];
  const float* b_o  = (const float*)d_in[10];
  const float* w_bd = (const float*)d_in[11];
  const float* b_bd = (const float*)d_in[12];
  const float* w_pr = (const float*)d_in[13];
  const float* b_pr = (const float*)d_in[14];
  float* out = (float*)d_out;

  const size_t M = (size_t)NB * NT;                       // 16384
  unsigned short* hhi = (unsigned short*)d_ws;            // M*NE u16
  unsigned short* qhi = hhi + M * NE;
  unsigned short* qlo = qhi + M * NE;
  unsigned short* khi = qlo + M * NE;
  unsigned short* klo = khi + M * NE;
  unsigned short* wfhi = klo + M * NE;                    // 832*256 u16 each
  unsigned short* wflo = wfhi + 212992;
  float* bias_f = (float*)(wflo + 212992);                // 832
  float* uvbuf  = bias_f + 832;                           // 1024
  float* vubuf  = uvbuf + 1024;                           // 65,536 [B,H,T]
  float* part   = vubuf + 65536;                          // 1,048,576 [bh][t][kh8][{l,sv}]
  float* bsbuf  = part + 1048576;                         // 16,384
  float* consts = bsbuf + 16384;                          // 8
  float* psum   = consts + 8;                             // 16,384
  int*   pid    = (int*)(psum + 16384);                   // 16,384
  int*   counts = pid + 16384;                            // 64

  setup1_kernel<<<1, 256, 0, stream>>>(w_o, b_o, w_bd, b_bd, w_v, b_v, uvbuf, consts);
  setup2_kernel<<<833, 256, 0, stream>>>(w_in, w_q, w_k, b_in, b_q, b_k,
      uvbuf, consts, wfhi, wflo, bias_f, psum);
  xgemm_kernel<<<1664, 256, 0, stream>>>(x, wfhi, wflo, bias_f,
      hhi, qhi, qlo, khi, klo, vubuf);
  attn_kernel9<<<2048, 512, 0, stream>>>(qhi, qlo, khi, klo, vubuf, (float2*)part);
  combine_kernel<<<64, 256, 0, stream>>>((const float4*)part, consts, bsbuf);
  boundary_kernel<<<8, 256, 0, stream>>>(bsbuf, pid, counts);
  pool_kernel<<<128, 256, 0, stream>>>(hhi, pid, psum);
  final_kernel<<<64, 256, 0, stream>>>(psum, counts, w_pr, b_pr, out);
}

// Round 13
// 171.127 us; speedup vs baseline: 1.0589x; 1.0589x over previous
//
#include <hip/hip_runtime.h>
#include <cstddef>

#define NB 8
#define NT 2048
#define NE 256
#define NH 4
#define ND 64
#define NP 8

typedef short bf16x8 __attribute__((ext_vector_type(8)));
typedef float f32x4 __attribute__((ext_vector_type(4)));

__device__ __forceinline__ unsigned short f2bf(float f) {
  unsigned u = __builtin_bit_cast(unsigned, f);
  u += 0x7fffu + ((u >> 16) & 1u);          // RNE
  return (unsigned short)(u >> 16);
}
__device__ __forceinline__ float bf2f(unsigned short h) {
  unsigned u = ((unsigned)h) << 16;
  return __builtin_bit_cast(float, u);
}
// packed hi/lo split of a float pair (integer-only)
__device__ __forceinline__ void split2(float a, float b, unsigned& hi, unsigned& lo) {
  const unsigned short ha = f2bf(a), hb = f2bf(b);
  hi = (unsigned)ha | ((unsigned)hb << 16);
  const unsigned short la = f2bf(a - bf2f(ha));
  const unsigned short lb = f2bf(b - bf2f(hb));
  lo = (unsigned)la | ((unsigned)lb << 16);
}
__device__ __forceinline__ void gld16(const void* g, void* l) {
  __builtin_amdgcn_global_load_lds((const __attribute__((address_space(1))) unsigned*)g,
                                   (__attribute__((address_space(3))) unsigned*)l, 16, 0, 0);
}

// q-prescale: 1/8 (attn scale) * log2(e) (exp2 domain for softmax)
#define QSC 0.180336880111120419f

// ---------------- setup1: u = w_bd@w_o ; uv_h ; consts (1 block) -----------------------
__global__ __launch_bounds__(256) void setup1_kernel(
    const float* __restrict__ w_o, const float* __restrict__ b_o,
    const float* __restrict__ w_bd, const float* __restrict__ b_bd,
    const float* __restrict__ w_v, const float* __restrict__ b_v,
    float* __restrict__ uvbuf, float* __restrict__ consts)
{
  __shared__ float wbd_s[NE];
  __shared__ float u_s[NE];
  const int tid = threadIdx.x;
  wbd_s[tid] = w_bd[tid];
  __syncthreads();
  float a = 0.f;
  for (int j = 0; j < NE; ++j) a = fmaf(wbd_s[j], w_o[j * NE + tid], a);
  u_s[tid] = a;
  __syncthreads();
  #pragma unroll
  for (int hh = 0; hh < NH; ++hh) {
    float a2 = 0.f;
    for (int d = 0; d < ND; ++d)
      a2 = fmaf(u_s[hh * ND + d], w_v[(size_t)(hh * ND + d) * NE + tid], a2);
    uvbuf[hh * NE + tid] = a2;
  }
  if (tid == 0) {
    float cc = 0.f;
    for (int j = 0; j < NE; ++j) cc = fmaf(wbd_s[j], b_o[j], cc);
    consts[0] = cc + b_bd[0];
  }
  if (tid >= 8 && tid < 12) {
    const int hh = tid - 8;
    float cv = 0.f;
    for (int d = 0; d < ND; ++d) cv = fmaf(u_s[hh * ND + d], b_v[hh * ND + d], cv);
    consts[1 + hh] = cv;
  }
}

// ---------------- setup2 v2: fused weight rows, 8 rows per block -----------------------
// blocks 0..31: copy w_in rows (8 each). blocks 32..96: rows 256..771 = {QSC*w_q, w_k,
// uv} @ w_in (8 rows each, w_in streamed once per block). block 97: zero psum.
// Pad rows 772..831 left as-is (their output cols are never written).
__global__ __launch_bounds__(256) void setup2_kernel(
    const float* __restrict__ w_in, const float* __restrict__ w_q,
    const float* __restrict__ w_k, const float* __restrict__ b_in,
    const float* __restrict__ b_q, const float* __restrict__ b_k,
    const float* __restrict__ uvbuf, const float* __restrict__ consts,
    unsigned short* __restrict__ wfhi, unsigned short* __restrict__ wflo,
    float* __restrict__ bias_f, float* __restrict__ psum)
{
  const int b = blockIdx.x, tid = threadIdx.x;
  if (b == 97) {
    for (int i = tid; i < NB * NP * NE; i += 256) psum[i] = 0.f;
    return;
  }
  if (b < 32) {                                           // plain w_in copy rows
    const int r0 = b * 8;
    #pragma unroll
    for (int j = 0; j < 8; ++j) {
      const int r = r0 + j;
      const float v = w_in[(size_t)r * 256 + tid];
      const unsigned short hb = f2bf(v);
      wfhi[(size_t)r * 256 + tid] = hb;
      wflo[(size_t)r * 256 + tid] = f2bf(v - bf2f(hb));
    }
    if (tid < 8) bias_f[r0 + tid] = b_in[r0 + tid];
    return;
  }
  // product blocks: rows r0..r0+7 of the fused matrix, r in [256, 772)
  __shared__ float row8[8][NE];
  __shared__ float b_in_s[NE];
  __shared__ float bias_s[8];
  const int r0 = 256 + (b - 32) * 8;
  b_in_s[tid] = b_in[tid];
  #pragma unroll
  for (int j = 0; j < 8; ++j) {
    const int r = r0 + j;
    float w = 0.f;
    if (r < 512)      w = w_q[(size_t)(r - 256) * 256 + tid];
    else if (r < 768) w = w_k[(size_t)(r - 512) * 256 + tid];
    else if (r < 772) w = uvbuf[(size_t)(r - 768) * 256 + tid];
    row8[j][tid] = w;
  }
  __syncthreads();
  float acc[8] = {};
  for (int e = 0; e < 256; ++e) {
    const float wv = w_in[(size_t)e * 256 + tid];
    #pragma unroll
    for (int j = 0; j < 8; ++j) acc[j] = fmaf(row8[j][e], wv, acc[j]);
  }
  // bias dots: half-wave group g handles row g
  {
    const int g = tid >> 5, l32 = tid & 31;
    float p = 0.f;
    #pragma unroll
    for (int m = 0; m < 8; ++m) p = fmaf(row8[g][l32 + 32 * m], b_in_s[l32 + 32 * m], p);
    p += __shfl_xor(p, 1);  p += __shfl_xor(p, 2);  p += __shfl_xor(p, 4);
    p += __shfl_xor(p, 8);  p += __shfl_xor(p, 16);
    if (l32 == 0) {
      const int r = r0 + g;
      float base = 0.f;
      if (r < 512)      base = b_q[r - 256];
      else if (r < 768) base = b_k[r - 512];
      else if (r < 772) base = consts[1 + (r - 768)];
      float bia = p + base;
      if (r < 512) bia *= QSC;
      bias_s[g] = bia;
    }
  }
  __syncthreads();
  #pragma unroll
  for (int j = 0; j < 8; ++j) {
    const int r = r0 + j;
    if (r >= 772) break;
    float v = acc[j];
    if (r < 512) v *= QSC;
    const unsigned short hb = f2bf(v);
    wfhi[(size_t)r * 256 + tid] = hb;
    wflo[(size_t)r * 256 + tid] = f2bf(v - bf2f(hb));
  }
  if (tid < 8 && r0 + tid < 772) bias_f[r0 + tid] = bias_s[tid];
}

// ---------------- xgemm: [h | q*QSC | k | vu] = x @ Wf^T + bias_f ----------------------
// BM=128 BN=64 BK=32; 256 thr / 4 waves; grid 1664 XCD-swizzled; A = x f32, in-reg split.
__global__ __launch_bounds__(256) void xgemm_kernel(
    const float* __restrict__ x,
    const unsigned short* __restrict__ wfhi, const unsigned short* __restrict__ wflo,
    const float* __restrict__ bias_f,
    unsigned short* __restrict__ hhi,
    unsigned short* __restrict__ Qhi, unsigned short* __restrict__ Qlo,
    unsigned short* __restrict__ Khi, unsigned short* __restrict__ Klo,
    float* __restrict__ vubuf)
{
  __shared__ __align__(16) char sm[2][24576];
  const int tid = threadIdx.x;
  const int wave = tid >> 6, lane = tid & 63;
  const int lr = lane & 15, lg = lane >> 4;
  const int wm = wave >> 1, wn = wave & 1;
  const int bid = blockIdx.x;
  const int idx = bid >> 3;                     // 0..207
  const int m0 = ((bid & 7) * 16 + idx / 13) * 128;
  const int n0 = (idx % 13) * 64;

  const float* aSrc[4];
  #pragma unroll
  for (int c = 0; c < 4; ++c) {
    const int L = c * 4096 + tid * 16;
    const int row = L >> 7, w = (L >> 4) & 7;
    aSrc[c] = x + (size_t)(m0 + row) * 256 + (w ^ (row & 7)) * 4;
  }
  const unsigned short* wSrc[2];
  #pragma unroll
  for (int c = 0; c < 2; ++c) {
    const int L = c * 4096 + tid * 16;
    const int half = (L >> 12) & 1;
    const int Lh = L & 4095;
    const int col = Lh >> 6, w = (Lh >> 4) & 3;
    wSrc[c] = (half ? wflo : wfhi) + (size_t)(n0 + col) * 256 + (w ^ ((col >> 1) & 3)) * 8;
  }
  int aoff[4][2], woff[2];
  #pragma unroll
  for (int s = 0; s < 4; ++s) {
    const int row = wm * 64 + s * 16 + lr;
    const int b0 = row * 128 + lg * 32;
    const int f = (row & 7) << 4;
    aoff[s][0] = b0 ^ f;
    aoff[s][1] = (b0 + 16) ^ f;
  }
  #pragma unroll
  for (int ns = 0; ns < 2; ++ns) {
    const int col = wn * 32 + ns * 16 + lr;
    woff[ns] = (col * 64 + lg * 16) ^ (((col >> 1) & 3) << 4);
  }

  f32x4 acc[4][2];
  #pragma unroll
  for (int s = 0; s < 4; ++s)
    #pragma unroll
    for (int ns = 0; ns < 2; ++ns) acc[s][ns] = (f32x4){0.f, 0.f, 0.f, 0.f};

  {
    char* lb = sm[0];
    #pragma unroll
    for (int c = 0; c < 4; ++c) gld16(aSrc[c], lb + c * 4096 + wave * 1024);
    #pragma unroll
    for (int c = 0; c < 2; ++c) gld16(wSrc[c], lb + 16384 + c * 4096 + wave * 1024);
  }

  for (int kt = 0; kt < 8; ++kt) {
    __syncthreads();
    if (kt < 7) {
      char* nb = sm[(kt + 1) & 1];
      #pragma unroll
      for (int c = 0; c < 4; ++c) gld16(aSrc[c] + (kt + 1) * 32, nb + c * 4096 + wave * 1024);
      #pragma unroll
      for (int c = 0; c < 2; ++c) gld16(wSrc[c] + (kt + 1) * 32, nb + 16384 + c * 4096 + wave * 1024);
    }
    const char* lb = sm[kt & 1];
    bf16x8 ah[4], al[4], wh[2], wl[2];
    #pragma unroll
    for (int s = 0; s < 4; ++s) {
      const f32x4 p0 = *(const f32x4*)(lb + aoff[s][0]);
      const f32x4 p1 = *(const f32x4*)(lb + aoff[s][1]);
      unsigned h0, h1, h2, h3, l0, l1, l2, l3;
      split2(p0[0], p0[1], h0, l0);
      split2(p0[2], p0[3], h1, l1);
      split2(p1[0], p1[1], h2, l2);
      split2(p1[2], p1[3], h3, l3);
      const uint4 hu = make_uint4(h0, h1, h2, h3);
      const uint4 lu = make_uint4(l0, l1, l2, l3);
      ah[s] = __builtin_bit_cast(bf16x8, hu);
      al[s] = __builtin_bit_cast(bf16x8, lu);
    }
    #pragma unroll
    for (int ns = 0; ns < 2; ++ns) {
      wh[ns] = *(const bf16x8*)(lb + 16384 + woff[ns]);
      wl[ns] = *(const bf16x8*)(lb + 20480 + woff[ns]);
    }
    #pragma unroll
    for (int s = 0; s < 4; ++s)
      #pragma unroll
      for (int ns = 0; ns < 2; ++ns) {
        acc[s][ns] = __builtin_amdgcn_mfma_f32_16x16x32_bf16(ah[s], wh[ns], acc[s][ns], 0, 0, 0);
        acc[s][ns] = __builtin_amdgcn_mfma_f32_16x16x32_bf16(ah[s], wl[ns], acc[s][ns], 0, 0, 0);
        acc[s][ns] = __builtin_amdgcn_mfma_f32_16x16x32_bf16(al[s], wh[ns], acc[s][ns], 0, 0, 0);
      }
  }
  #pragma unroll
  for (int s = 0; s < 4; ++s)
    #pragma unroll
    for (int ns = 0; ns < 2; ++ns)
      #pragma unroll
      for (int reg = 0; reg < 4; ++reg) {
        const int row = m0 + wm * 64 + s * 16 + lg * 4 + reg;
        const int col = n0 + wn * 32 + ns * 16 + lr;
        const float v = acc[s][ns][reg] + bias_f[col];
        const int b = row >> 11, t = row & 2047;
        if (col < 256) {
          hhi[(size_t)row * 256 + col] = f2bf(v);
        } else if (col < 768) {
          const int c = (col - 256) & 255;
          const int head = c >> 6, d = c & 63;
          const size_t i2 = (((size_t)(b * NH + head)) * NT + t) * ND + d;
          const unsigned short hb = f2bf(v);
          const unsigned short lb2 = f2bf(v - bf2f(hb));
          if (col < 512) { Qhi[i2] = hb; Qlo[i2] = lb2; }
          else           { Khi[i2] = hb; Klo[i2] = lb2; }
        } else if (col < 772) {
          vubuf[((size_t)(b * NH + (col - 768))) * NT + t] = v;
        }
      }
}

// ---------------- attention v8: stage-once + WAVE-STAGGERED tile order (R11 best) ------
// split-K x8: 2048 blocks; block = 256 q x 256 k (4 tiles staged upfront, 1 barrier).
// 512 thr / 8 waves; wave = 32 q-rows. exp2-domain softmax (q pre-scaled by QSC).
__global__ __launch_bounds__(512) void attn_kernel8(
    const unsigned short* __restrict__ qhi, const unsigned short* __restrict__ qlo,
    const unsigned short* __restrict__ khi, const unsigned short* __restrict__ klo,
    const float* __restrict__ vu, float2* __restrict__ part2)
{
  __shared__ __align__(16) char kbuf[4][16384];   // 4 tiles x [hi 8KB | lo 8KB], swizzled
  __shared__ float vu_s[256];
  const int tid = threadIdx.x;
  const int wave = tid >> 6, lane = tid & 63;
  const int lr = lane & 15, lg = lane >> 4;
  const int bid = blockIdx.x;                     // 0..2047
  const int idx = bid >> 3;                       // 0..255
  const int bh = (bid & 7) * 4 + (idx >> 6);
  const int rem = idx & 63;
  const int qt = rem >> 3, kh = rem & 7;
  const size_t base = (size_t)bh * NT * ND;
  const int qrow0 = qt * 256 + wave * 32;
  const int krow0 = kh * 256;

  if (tid < 256) vu_s[tid] = vu[(size_t)bh * NT + krow0 + tid];

  bf16x8 qf[2][2][2];
  #pragma unroll
  for (int s = 0; s < 2; ++s)
    #pragma unroll
    for (int ds = 0; ds < 2; ++ds) {
      const size_t off = base + (size_t)(qrow0 + s * 16 + lr) * ND + ds * 32 + lg * 8;
      qf[s][ds][0] = *(const bf16x8*)(qhi + off);
      qf[s][ds][1] = *(const bf16x8*)(qlo + off);
    }

  const int so = (tid * 16) ^ (((tid >> 3) & 7) << 4);
  int ro0[4], ro1[4];
  #pragma unroll
  for (int ns = 0; ns < 4; ++ns) {
    const int r = ns * 16 + lr;
    const int sw = (r & 7) << 4;
    const int ob = r * 128 + lg * 16;
    ro0[ns] = ob ^ sw;
    ro1[ns] = (ob + 64) ^ sw;
  }
  const char* srcH = (const char*)(khi + base + (size_t)krow0 * ND);
  const char* srcL = (const char*)(klo + base + (size_t)krow0 * ND);
  #pragma unroll
  for (int t = 0; t < 4; ++t) {
    gld16(srcH + t * 8192 + so, &kbuf[t][wave * 1024]);
    gld16(srcL + t * 8192 + so, &kbuf[t][8192 + wave * 1024]);
  }
  __syncthreads();                                // only barrier

  float l[8], sv[8];
  #pragma unroll
  for (int i = 0; i < 8; ++i) { l[i] = 0.f; sv[i] = 0.f; }
  const f32x4 Z = (f32x4){0.f, 0.f, 0.f, 0.f};    // persistent zero C-operand

  #pragma unroll
  for (int it = 0; it < 4; ++it) {
    const int kt = (it + wave) & 3;               // wave-staggered tile order
    const char* kb = (const char*)kbuf[kt];
    f32x4 acc[2][4];
    float vuv[4];
    __builtin_amdgcn_s_setprio(1);
    #pragma unroll
    for (int ns = 0; ns < 4; ++ns) {
      const bf16x8 kh0 = *(const bf16x8*)(kb + ro0[ns]);
      const bf16x8 kh1 = *(const bf16x8*)(kb + ro1[ns]);
      const bf16x8 kl0 = *(const bf16x8*)(kb + 8192 + ro0[ns]);
      const bf16x8 kl1 = *(const bf16x8*)(kb + 8192 + ro1[ns]);
      vuv[ns] = vu_s[kt * 64 + ns * 16 + lr];
      #pragma unroll
      for (int s = 0; s < 2; ++s) {
        acc[s][ns] = __builtin_amdgcn_mfma_f32_16x16x32_bf16(qf[s][0][0], kh0, Z, 0, 0, 0);
        acc[s][ns] = __builtin_amdgcn_mfma_f32_16x16x32_bf16(qf[s][0][0], kl0, acc[s][ns], 0, 0, 0);
        acc[s][ns] = __builtin_amdgcn_mfma_f32_16x16x32_bf16(qf[s][0][1], kh0, acc[s][ns], 0, 0, 0);
        acc[s][ns] = __builtin_amdgcn_mfma_f32_16x16x32_bf16(qf[s][1][0], kh1, acc[s][ns], 0, 0, 0);
        acc[s][ns] = __builtin_amdgcn_mfma_f32_16x16x32_bf16(qf[s][1][0], kl1, acc[s][ns], 0, 0, 0);
        acc[s][ns] = __builtin_amdgcn_mfma_f32_16x16x32_bf16(qf[s][1][1], kh1, acc[s][ns], 0, 0, 0);
      }
    }
    __builtin_amdgcn_s_setprio(0);
    #pragma unroll
    for (int s = 0; s < 2; ++s)
      #pragma unroll
      for (int reg = 0; reg < 4; ++reg) {
        const int ri = s * 4 + reg;
        #pragma unroll
        for (int ns = 0; ns < 4; ++ns) {
          const float e = __builtin_amdgcn_exp2f(acc[s][ns][reg]);
          l[ri] += e;
          sv[ri] = fmaf(e, vuv[ns], sv[ri]);
        }
      }
  }
  #pragma unroll
  for (int ri = 0; ri < 8; ++ri) {
    #pragma unroll
    for (int off = 1; off < 16; off <<= 1) {
      l[ri]  += __shfl_xor(l[ri],  off, 16);
      sv[ri] += __shfl_xor(sv[ri], off, 16);
    }
  }
  if (lr == 0) {
    #pragma unroll
    for (int s = 0; s < 2; ++s)
      #pragma unroll
      for (int reg = 0; reg < 4; ++reg) {
        const int row = qrow0 + s * 16 + lg * 4 + reg;
        part2[(((size_t)bh * NT + row) << 3) + kh] = make_float2(l[s * 4 + reg], sv[s * 4 + reg]);
      }
  }
}

// ---------------- combine: reduce split-K x8 partials -> bs = sigmoid(logit) -----------
__global__ __launch_bounds__(256) void combine_kernel(
    const float4* __restrict__ part4, const float* __restrict__ consts,
    float* __restrict__ bs)
{
  const int gid = blockIdx.x * 256 + threadIdx.x;    // 0..16383
  const int b = gid >> 11, t = gid & 2047;
  float logit = consts[0];
  #pragma unroll
  for (int hh = 0; hh < NH; ++hh) {
    const size_t p0 = ((size_t)((b * NH + hh) * NT) + t) * 4;   // 4 float4 = 8 {l,sv}
    float lsum = 0.f, ssum = 0.f;
    #pragma unroll
    for (int q = 0; q < 4; ++q) {
      const float4 p = part4[p0 + q];
      lsum += p.x + p.z;
      ssum += p.y + p.w;
    }
    logit += ssum / lsum;
  }
  bs[gid] = 1.f / (1.f + expf(-logit));
}

// ---------------- boundary: cumsum bs, pid, counts (one block per batch) ---------------
__global__ __launch_bounds__(256) void boundary_kernel(
    const float* __restrict__ bs, int* __restrict__ pid, int* __restrict__ counts)
{
  const int b = blockIdx.x, tid = threadIdx.x;
  __shared__ float partial[256];
  __shared__ int cnt_s[8];
  float v[8];
  float run = 0.f;
  const float4 b0 = *(const float4*)(bs + b * NT + tid * 8);
  const float4 b1 = *(const float4*)(bs + b * NT + tid * 8 + 4);
  const float bv[8] = {b0.x, b0.y, b0.z, b0.w, b1.x, b1.y, b1.z, b1.w};
  #pragma unroll
  for (int i = 0; i < 8; ++i) { run += bv[i]; v[i] = run; }
  float x = run;
  partial[tid] = x;
  __syncthreads();
  for (int off = 1; off < 256; off <<= 1) {
    const float y = (tid >= off) ? partial[tid - off] : 0.f;
    __syncthreads();
    x += y;
    partial[tid] = x;
    __syncthreads();
  }
  const float total = partial[255];
  if (tid < 8) cnt_s[tid] = 0;
  __syncthreads();
  const float denom = fmaxf(total, 1e-6f);
  const float excl = x - run;
  #pragma unroll
  for (int i = 0; i < 8; ++i) {
    const float norm = (excl + v[i]) / denom;
    int pp = (int)(norm * 8.f);
    pp = pp > 7 ? 7 : pp;
    pid[b * NT + tid * 8 + i] = pp;
    atomicAdd(&cnt_s[pp], 1);
  }
  __syncthreads();
  if (tid < 8) counts[b * 8 + tid] = cnt_s[tid];
}

// ---------------- pool hhi into patch sums (branchless 8-way select) -------------------
__global__ __launch_bounds__(256) void pool_kernel(
    const unsigned short* __restrict__ hhi, const int* __restrict__ pid,
    float* __restrict__ psum)
{
  const int b = blockIdx.x >> 4, chunk = blockIdx.x & 15;
  const int tid = threadIdx.x;
  __shared__ int pid_s[128];
  const int t0 = chunk * 128;
  if (tid < 128) pid_s[tid] = pid[b * NT + t0 + tid];
  __syncthreads();
  float acc[8] = {};
  for (int tok = 0; tok < 128; ++tok) {
    const float val = bf2f(hhi[((size_t)b * NT + t0 + tok) * NE + tid]);
    const int p = pid_s[tok];
    #pragma unroll
    for (int pp = 0; pp < 8; ++pp) acc[pp] += (p == pp) ? val : 0.f;
  }
  #pragma unroll
  for (int pp = 0; pp < 8; ++pp)
    atomicAdd(&psum[((size_t)b * NP + pp) * NE + tid], acc[pp]);
}

// ---------------- final: out = (psum/count) @ w_pr^T + b_pr ---------------------------
__global__ __launch_bounds__(256) void final_kernel(
    const float* __restrict__ psum, const int* __restrict__ counts,
    const float* __restrict__ w_pr, const float* __restrict__ b_pr, float* __restrict__ out)
{
  const int bp = blockIdx.x;
  const int tid = threadIdx.x;
  __shared__ float pe[NE];
  const float cnt = fmaxf((float)counts[bp], 1.f);
  pe[tid] = psum[(size_t)bp * NE + tid] / cnt;
  __syncthreads();
  float acc = 0.f;
  for (int e = 0; e < NE; ++e) acc = fmaf(pe[e], w_pr[(size_t)tid * NE + e], acc);
  out[(size_t)bp * NE + tid] = acc + b_pr[tid];
}

extern "C" void kernel_launch(void* const* d_in, const int* in_sizes, int n_in,
                              void* d_out, int out_size, void* d_ws, size_t ws_size,
                              hipStream_t stream) {
  (void)in_sizes; (void)n_in; (void)out_size; (void)ws_size;
  const float* x    = (const float*)d_in[0];
  const float* w_in = (const float*)d_in[1];
  const float* b_in = (const float*)d_in[2];
  const float* w_q  = (const float*)d_in[3];
  const float* b_q  = (const float*)d_in[4];
  const float* w_k  = (const float*)d_in[5];
  const float* b_k  = (const float*)d_in[6];
  const float* w_v  = (const float*)d_in[7];
  const float* b_v  = (const float*)d_in[8];
  const float* w_o  = (const float*)d_in[9];
  const float* b_o  = (const float*)d_in[10];
  const float* w_bd = (const float*)d_in[11];
  const float* b_bd = (const float*)d_in[12];
  const float* w_pr = (const float*)d_in[13];
  const float* b_pr = (const float*)d_in[14];
  float* out = (float*)d_out;

  const size_t M = (size_t)NB * NT;                       // 16384
  unsigned short* hhi = (unsigned short*)d_ws;            // M*NE u16
  unsigned short* qhi = hhi + M * NE;
  unsigned short* qlo = qhi + M * NE;
  unsigned short* khi = qlo + M * NE;
  unsigned short* klo = khi + M * NE;
  unsigned short* wfhi = klo + M * NE;                    // 832*256 u16 each
  unsigned short* wflo = wfhi + 212992;
  float* bias_f = (float*)(wflo + 212992);                // 832
  float* uvbuf  = bias_f + 832;                           // 1024
  float* vubuf  = uvbuf + 1024;                           // 65,536 [B,H,T]
  float* part   = vubuf + 65536;                          // 1,048,576 [bh][t][kh8][{l,sv}]
  float* bsbuf  = part + 1048576;                         // 16,384
  float* consts = bsbuf + 16384;                          // 8
  float* psum   = consts + 8;                             // 16,384
  int*   pid    = (int*)(psum + 16384);                   // 16,384
  int*   counts = pid + 16384;                            // 64

  setup1_kernel<<<1, 256, 0, stream>>>(w_o, b_o, w_bd, b_bd, w_v, b_v, uvbuf, consts);
  setup2_kernel<<<98, 256, 0, stream>>>(w_in, w_q, w_k, b_in, b_q, b_k,
      uvbuf, consts, wfhi, wflo, bias_f, psum);
  xgemm_kernel<<<1664, 256, 0, stream>>>(x, wfhi, wflo, bias_f,
      hhi, qhi, qlo, khi, klo, vubuf);
  attn_kernel8<<<2048, 512, 0, stream>>>(qhi, qlo, khi, klo, vubuf, (float2*)part);
  combine_kernel<<<64, 256, 0, stream>>>((const float4*)part, consts, bsbuf);
  boundary_kernel<<<8, 256, 0, stream>>>(bsbuf, pid, counts);
  pool_kernel<<<128, 256, 0, stream>>>(hhi, pid, psum);
  final_kernel<<<64, 256, 0, stream>>>(psum, counts, w_pr, b_pr, out);
}

// Round 14
// 166.786 us; speedup vs baseline: 1.0865x; 1.0260x over previous
//
#include <hip/hip_runtime.h>
#include <cstddef>

#define NB 8
#define NT 2048
#define NE 256
#define NH 4
#define ND 64
#define NP 8

typedef short bf16x8 __attribute__((ext_vector_type(8)));
typedef float f32x4 __attribute__((ext_vector_type(4)));

__device__ __forceinline__ unsigned short f2bf(float f) {
  unsigned u = __builtin_bit_cast(unsigned, f);
  u += 0x7fffu + ((u >> 16) & 1u);          // RNE
  return (unsigned short)(u >> 16);
}
__device__ __forceinline__ float bf2f(unsigned short h) {
  unsigned u = ((unsigned)h) << 16;
  return __builtin_bit_cast(float, u);
}
// packed hi/lo split of a float pair (integer-only)
__device__ __forceinline__ void split2(float a, float b, unsigned& hi, unsigned& lo) {
  const unsigned short ha = f2bf(a), hb = f2bf(b);
  hi = (unsigned)ha | ((unsigned)hb << 16);
  const unsigned short la = f2bf(a - bf2f(ha));
  const unsigned short lb = f2bf(b - bf2f(hb));
  lo = (unsigned)la | ((unsigned)lb << 16);
}
__device__ __forceinline__ void gld16(const void* g, void* l) {
  __builtin_amdgcn_global_load_lds((const __attribute__((address_space(1))) unsigned*)g,
                                   (__attribute__((address_space(3))) unsigned*)l, 16, 0, 0);
}

// q-prescale: 1/8 (attn scale) * log2(e) (exp2 domain for softmax)
#define QSC 0.180336880111120419f

// ---------------- setup1: u = w_bd@w_o ; uv_h ; consts (1 block) -----------------------
__global__ __launch_bounds__(256) void setup1_kernel(
    const float* __restrict__ w_o, const float* __restrict__ b_o,
    const float* __restrict__ w_bd, const float* __restrict__ b_bd,
    const float* __restrict__ w_v, const float* __restrict__ b_v,
    float* __restrict__ uvbuf, float* __restrict__ consts)
{
  __shared__ float wbd_s[NE];
  __shared__ float u_s[NE];
  const int tid = threadIdx.x;
  wbd_s[tid] = w_bd[tid];
  __syncthreads();
  float a = 0.f;
  for (int j = 0; j < NE; ++j) a = fmaf(wbd_s[j], w_o[j * NE + tid], a);
  u_s[tid] = a;
  __syncthreads();
  #pragma unroll
  for (int hh = 0; hh < NH; ++hh) {
    float a2 = 0.f;
    for (int d = 0; d < ND; ++d)
      a2 = fmaf(u_s[hh * ND + d], w_v[(size_t)(hh * ND + d) * NE + tid], a2);
    uvbuf[hh * NE + tid] = a2;
  }
  if (tid == 0) {
    float cc = 0.f;
    for (int j = 0; j < NE; ++j) cc = fmaf(wbd_s[j], b_o[j], cc);
    consts[0] = cc + b_bd[0];
  }
  if (tid >= 8 && tid < 12) {
    const int hh = tid - 8;
    float cv = 0.f;
    for (int d = 0; d < ND; ++d) cv = fmaf(u_s[hh * ND + d], b_v[hh * ND + d], cv);
    consts[1 + hh] = cv;
  }
}

// ---------------- setup2 v2: fused weight rows, 8 rows per block -----------------------
__global__ __launch_bounds__(256) void setup2_kernel(
    const float* __restrict__ w_in, const float* __restrict__ w_q,
    const float* __restrict__ w_k, const float* __restrict__ b_in,
    const float* __restrict__ b_q, const float* __restrict__ b_k,
    const float* __restrict__ uvbuf, const float* __restrict__ consts,
    unsigned short* __restrict__ wfhi, unsigned short* __restrict__ wflo,
    float* __restrict__ bias_f, float* __restrict__ psum)
{
  const int b = blockIdx.x, tid = threadIdx.x;
  if (b == 97) {
    for (int i = tid; i < NB * NP * NE; i += 256) psum[i] = 0.f;
    return;
  }
  if (b < 32) {                                           // plain w_in copy rows
    const int r0 = b * 8;
    #pragma unroll
    for (int j = 0; j < 8; ++j) {
      const int r = r0 + j;
      const float v = w_in[(size_t)r * 256 + tid];
      const unsigned short hb = f2bf(v);
      wfhi[(size_t)r * 256 + tid] = hb;
      wflo[(size_t)r * 256 + tid] = f2bf(v - bf2f(hb));
    }
    if (tid < 8) bias_f[r0 + tid] = b_in[r0 + tid];
    return;
  }
  __shared__ float row8[8][NE];
  __shared__ float b_in_s[NE];
  __shared__ float bias_s[8];
  const int r0 = 256 + (b - 32) * 8;
  b_in_s[tid] = b_in[tid];
  #pragma unroll
  for (int j = 0; j < 8; ++j) {
    const int r = r0 + j;
    float w = 0.f;
    if (r < 512)      w = w_q[(size_t)(r - 256) * 256 + tid];
    else if (r < 768) w = w_k[(size_t)(r - 512) * 256 + tid];
    else if (r < 772) w = uvbuf[(size_t)(r - 768) * 256 + tid];
    row8[j][tid] = w;
  }
  __syncthreads();
  float acc[8] = {};
  for (int e = 0; e < 256; ++e) {
    const float wv = w_in[(size_t)e * 256 + tid];
    #pragma unroll
    for (int j = 0; j < 8; ++j) acc[j] = fmaf(row8[j][e], wv, acc[j]);
  }
  {
    const int g = tid >> 5, l32 = tid & 31;
    float p = 0.f;
    #pragma unroll
    for (int m = 0; m < 8; ++m) p = fmaf(row8[g][l32 + 32 * m], b_in_s[l32 + 32 * m], p);
    p += __shfl_xor(p, 1);  p += __shfl_xor(p, 2);  p += __shfl_xor(p, 4);
    p += __shfl_xor(p, 8);  p += __shfl_xor(p, 16);
    if (l32 == 0) {
      const int r = r0 + g;
      float base = 0.f;
      if (r < 512)      base = b_q[r - 256];
      else if (r < 768) base = b_k[r - 512];
      else if (r < 772) base = consts[1 + (r - 768)];
      float bia = p + base;
      if (r < 512) bia *= QSC;
      bias_s[g] = bia;
    }
  }
  __syncthreads();
  #pragma unroll
  for (int j = 0; j < 8; ++j) {
    const int r = r0 + j;
    if (r >= 772) break;
    float v = acc[j];
    if (r < 512) v *= QSC;
    const unsigned short hb = f2bf(v);
    wfhi[(size_t)r * 256 + tid] = hb;
    wflo[(size_t)r * 256 + tid] = f2bf(v - bf2f(hb));
  }
  if (tid < 8 && r0 + tid < 772) bias_f[r0 + tid] = bias_s[tid];
}

// ---------------- xgemm v3: reg-staged A conversion, bf16 LDS, dbuf --------------------
// [h | q*QSC | k | vu] = x @ Wf^T + bias_f. BM=128 BN=64 BK=32; 256 thr / 4 waves.
// A: global f32 -> regs -> split2 -> ds_write bf16 (conflict-free qkvgemm layout).
// W: gld16 direct (bf16). One barrier per k-step. Grid 1664 XCD-swizzled.
__global__ __launch_bounds__(256) void xgemm_kernel(
    const float* __restrict__ x,
    const unsigned short* __restrict__ wfhi, const unsigned short* __restrict__ wflo,
    const float* __restrict__ bias_f,
    unsigned short* __restrict__ hhi,
    unsigned short* __restrict__ Qhi, unsigned short* __restrict__ Qlo,
    unsigned short* __restrict__ Khi, unsigned short* __restrict__ Klo,
    float* __restrict__ vubuf)
{
  __shared__ __align__(16) char sm[2][24576];   // Ahi 8K | Alo 8K | Whi 4K | Wlo 4K
  const int tid = threadIdx.x;
  const int wave = tid >> 6, lane = tid & 63;
  const int lr = lane & 15, lg = lane >> 4;
  const int wm = wave >> 1, wn = wave & 1;
  const int bid = blockIdx.x;
  const int idx = bid >> 3;                     // 0..207
  const int m0 = ((bid & 7) * 16 + idx / 13) * 128;
  const int n0 = (idx % 13) * 64;

  // A reg-staging: thread -> row = tid>>1, col-half = (tid&1)*16 (16 f32 per k-step)
  const int arow = tid >> 1;
  const int acolh = (tid & 1) * 16;
  const float* axp = x + (size_t)(m0 + arow) * 256 + acolh;
  const int asw = ((arow >> 1) & 3) << 4;
  const int aw0 = (arow * 64 + acolh * 2) ^ asw;
  const int aw1 = (arow * 64 + acolh * 2 + 16) ^ asw;

  // W staging sources (pre-swizzled global, linear LDS dest)
  const unsigned short* wSrc[2];
  #pragma unroll
  for (int c = 0; c < 2; ++c) {
    const int L = c * 4096 + tid * 16;
    const int half = (L >> 12) & 1;
    const int Lh = L & 4095;
    const int col = Lh >> 6, w = (Lh >> 4) & 3;
    wSrc[c] = (half ? wflo : wfhi) + (size_t)(n0 + col) * 256 + (w ^ ((col >> 1) & 3)) * 8;
  }
  // fragment read offsets (same involution)
  int aoff[4], woff[2];
  #pragma unroll
  for (int s = 0; s < 4; ++s) {
    const int row = wm * 64 + s * 16 + lr;
    aoff[s] = (row * 64 + lg * 16) ^ (((row >> 1) & 3) << 4);
  }
  #pragma unroll
  for (int ns = 0; ns < 2; ++ns) {
    const int col = wn * 32 + ns * 16 + lr;
    woff[ns] = (col * 64 + lg * 16) ^ (((col >> 1) & 3) << 4);
  }

  f32x4 acc[4][2];
  #pragma unroll
  for (int s = 0; s < 4; ++s)
    #pragma unroll
    for (int ns = 0; ns < 2; ++ns) acc[s][ns] = (f32x4){0.f, 0.f, 0.f, 0.f};

  f32x4 ar[4];
  #pragma unroll
  for (int j = 0; j < 4; ++j) ar[j] = *(const f32x4*)(axp + j * 4);
  {
    char* lb = sm[0];
    #pragma unroll
    for (int c = 0; c < 2; ++c) gld16(wSrc[c], lb + 16384 + c * 4096 + wave * 1024);
    unsigned h[8], l[8];
    #pragma unroll
    for (int j = 0; j < 4; ++j) {
      split2(ar[j][0], ar[j][1], h[j * 2], l[j * 2]);
      split2(ar[j][2], ar[j][3], h[j * 2 + 1], l[j * 2 + 1]);
    }
    *(uint4*)(lb + aw0)        = make_uint4(h[0], h[1], h[2], h[3]);
    *(uint4*)(lb + aw1)        = make_uint4(h[4], h[5], h[6], h[7]);
    *(uint4*)(lb + 8192 + aw0) = make_uint4(l[0], l[1], l[2], l[3]);
    *(uint4*)(lb + 8192 + aw1) = make_uint4(l[4], l[5], l[6], l[7]);
  }
  __syncthreads();

  for (int kt = 0; kt < 8; ++kt) {
    const char* lb = sm[kt & 1];
    char* nb = sm[(kt + 1) & 1];
    if (kt < 7) {
      #pragma unroll
      for (int c = 0; c < 2; ++c) gld16(wSrc[c] + (kt + 1) * 32, nb + 16384 + c * 4096 + wave * 1024);
      #pragma unroll
      for (int j = 0; j < 4; ++j) ar[j] = *(const f32x4*)(axp + (kt + 1) * 32 + j * 4);
    }
    bf16x8 ah[4], al[4], wh[2], wl[2];
    #pragma unroll
    for (int s = 0; s < 4; ++s) {
      ah[s] = *(const bf16x8*)(lb + aoff[s]);
      al[s] = *(const bf16x8*)(lb + 8192 + aoff[s]);
    }
    #pragma unroll
    for (int ns = 0; ns < 2; ++ns) {
      wh[ns] = *(const bf16x8*)(lb + 16384 + woff[ns]);
      wl[ns] = *(const bf16x8*)(lb + 20480 + woff[ns]);
    }
    #pragma unroll
    for (int s = 0; s < 4; ++s)
      #pragma unroll
      for (int ns = 0; ns < 2; ++ns) {
        acc[s][ns] = __builtin_amdgcn_mfma_f32_16x16x32_bf16(ah[s], wh[ns], acc[s][ns], 0, 0, 0);
        acc[s][ns] = __builtin_amdgcn_mfma_f32_16x16x32_bf16(ah[s], wl[ns], acc[s][ns], 0, 0, 0);
        acc[s][ns] = __builtin_amdgcn_mfma_f32_16x16x32_bf16(al[s], wh[ns], acc[s][ns], 0, 0, 0);
      }
    if (kt < 7) {
      unsigned h[8], l[8];
      #pragma unroll
      for (int j = 0; j < 4; ++j) {
        split2(ar[j][0], ar[j][1], h[j * 2], l[j * 2]);
        split2(ar[j][2], ar[j][3], h[j * 2 + 1], l[j * 2 + 1]);
      }
      *(uint4*)(nb + aw0)        = make_uint4(h[0], h[1], h[2], h[3]);
      *(uint4*)(nb + aw1)        = make_uint4(h[4], h[5], h[6], h[7]);
      *(uint4*)(nb + 8192 + aw0) = make_uint4(l[0], l[1], l[2], l[3]);
      *(uint4*)(nb + 8192 + aw1) = make_uint4(l[4], l[5], l[6], l[7]);
    }
    __syncthreads();
  }
  #pragma unroll
  for (int s = 0; s < 4; ++s)
    #pragma unroll
    for (int ns = 0; ns < 2; ++ns)
      #pragma unroll
      for (int reg = 0; reg < 4; ++reg) {
        const int row = m0 + wm * 64 + s * 16 + lg * 4 + reg;
        const int col = n0 + wn * 32 + ns * 16 + lr;
        const float v = acc[s][ns][reg] + bias_f[col];
        const int b = row >> 11, t = row & 2047;
        if (col < 256) {
          hhi[(size_t)row * 256 + col] = f2bf(v);
        } else if (col < 768) {
          const int c = (col - 256) & 255;
          const int head = c >> 6, d = c & 63;
          const size_t i2 = (((size_t)(b * NH + head)) * NT + t) * ND + d;
          const unsigned short hb = f2bf(v);
          const unsigned short lb2 = f2bf(v - bf2f(hb));
          if (col < 512) { Qhi[i2] = hb; Qlo[i2] = lb2; }
          else           { Khi[i2] = hb; Klo[i2] = lb2; }
        } else if (col < 772) {
          vubuf[((size_t)(b * NH + (col - 768))) * NT + t] = v;
        }
      }
}

// ---------------- attention v8: stage-once + wave-staggered tile order (best) ----------
__global__ __launch_bounds__(512) void attn_kernel8(
    const unsigned short* __restrict__ qhi, const unsigned short* __restrict__ qlo,
    const unsigned short* __restrict__ khi, const unsigned short* __restrict__ klo,
    const float* __restrict__ vu, float2* __restrict__ part2)
{
  __shared__ __align__(16) char kbuf[4][16384];   // 4 tiles x [hi 8KB | lo 8KB], swizzled
  __shared__ float vu_s[256];
  const int tid = threadIdx.x;
  const int wave = tid >> 6, lane = tid & 63;
  const int lr = lane & 15, lg = lane >> 4;
  const int bid = blockIdx.x;                     // 0..2047
  const int idx = bid >> 3;                       // 0..255
  const int bh = (bid & 7) * 4 + (idx >> 6);
  const int rem = idx & 63;
  const int qt = rem >> 3, kh = rem & 7;
  const size_t base = (size_t)bh * NT * ND;
  const int qrow0 = qt * 256 + wave * 32;
  const int krow0 = kh * 256;

  if (tid < 256) vu_s[tid] = vu[(size_t)bh * NT + krow0 + tid];

  bf16x8 qf[2][2][2];
  #pragma unroll
  for (int s = 0; s < 2; ++s)
    #pragma unroll
    for (int ds = 0; ds < 2; ++ds) {
      const size_t off = base + (size_t)(qrow0 + s * 16 + lr) * ND + ds * 32 + lg * 8;
      qf[s][ds][0] = *(const bf16x8*)(qhi + off);
      qf[s][ds][1] = *(const bf16x8*)(qlo + off);
    }

  const int so = (tid * 16) ^ (((tid >> 3) & 7) << 4);
  int ro0[4], ro1[4];
  #pragma unroll
  for (int ns = 0; ns < 4; ++ns) {
    const int r = ns * 16 + lr;
    const int sw = (r & 7) << 4;
    const int ob = r * 128 + lg * 16;
    ro0[ns] = ob ^ sw;
    ro1[ns] = (ob + 64) ^ sw;
  }
  const char* srcH = (const char*)(khi + base + (size_t)krow0 * ND);
  const char* srcL = (const char*)(klo + base + (size_t)krow0 * ND);
  #pragma unroll
  for (int t = 0; t < 4; ++t) {
    gld16(srcH + t * 8192 + so, &kbuf[t][wave * 1024]);
    gld16(srcL + t * 8192 + so, &kbuf[t][8192 + wave * 1024]);
  }
  __syncthreads();                                // only barrier

  float l[8], sv[8];
  #pragma unroll
  for (int i = 0; i < 8; ++i) { l[i] = 0.f; sv[i] = 0.f; }
  const f32x4 Z = (f32x4){0.f, 0.f, 0.f, 0.f};    // persistent zero C-operand

  #pragma unroll
  for (int it = 0; it < 4; ++it) {
    const int kt = (it + wave) & 3;               // wave-staggered tile order
    const char* kb = (const char*)kbuf[kt];
    f32x4 acc[2][4];
    float vuv[4];
    __builtin_amdgcn_s_setprio(1);
    #pragma unroll
    for (int ns = 0; ns < 4; ++ns) {
      const bf16x8 kh0 = *(const bf16x8*)(kb + ro0[ns]);
      const bf16x8 kh1 = *(const bf16x8*)(kb + ro1[ns]);
      const bf16x8 kl0 = *(const bf16x8*)(kb + 8192 + ro0[ns]);
      const bf16x8 kl1 = *(const bf16x8*)(kb + 8192 + ro1[ns]);
      vuv[ns] = vu_s[kt * 64 + ns * 16 + lr];
      #pragma unroll
      for (int s = 0; s < 2; ++s) {
        acc[s][ns] = __builtin_amdgcn_mfma_f32_16x16x32_bf16(qf[s][0][0], kh0, Z, 0, 0, 0);
        acc[s][ns] = __builtin_amdgcn_mfma_f32_16x16x32_bf16(qf[s][0][0], kl0, acc[s][ns], 0, 0, 0);
        acc[s][ns] = __builtin_amdgcn_mfma_f32_16x16x32_bf16(qf[s][0][1], kh0, acc[s][ns], 0, 0, 0);
        acc[s][ns] = __builtin_amdgcn_mfma_f32_16x16x32_bf16(qf[s][1][0], kh1, acc[s][ns], 0, 0, 0);
        acc[s][ns] = __builtin_amdgcn_mfma_f32_16x16x32_bf16(qf[s][1][0], kl1, acc[s][ns], 0, 0, 0);
        acc[s][ns] = __builtin_amdgcn_mfma_f32_16x16x32_bf16(qf[s][1][1], kh1, acc[s][ns], 0, 0, 0);
      }
    }
    __builtin_amdgcn_s_setprio(0);
    #pragma unroll
    for (int s = 0; s < 2; ++s)
      #pragma unroll
      for (int reg = 0; reg < 4; ++reg) {
        const int ri = s * 4 + reg;
        #pragma unroll
        for (int ns = 0; ns < 4; ++ns) {
          const float e = __builtin_amdgcn_exp2f(acc[s][ns][reg]);
          l[ri] += e;
          sv[ri] = fmaf(e, vuv[ns], sv[ri]);
        }
      }
  }
  #pragma unroll
  for (int ri = 0; ri < 8; ++ri) {
    #pragma unroll
    for (int off = 1; off < 16; off <<= 1) {
      l[ri]  += __shfl_xor(l[ri],  off, 16);
      sv[ri] += __shfl_xor(sv[ri], off, 16);
    }
  }
  if (lr == 0) {
    #pragma unroll
    for (int s = 0; s < 2; ++s)
      #pragma unroll
      for (int reg = 0; reg < 4; ++reg) {
        const int row = qrow0 + s * 16 + lg * 4 + reg;
        part2[(((size_t)bh * NT + row) << 3) + kh] = make_float2(l[s * 4 + reg], sv[s * 4 + reg]);
      }
  }
}

// ---------------- combine: reduce split-K x8 partials -> bs = sigmoid(logit) -----------
__global__ __launch_bounds__(256) void combine_kernel(
    const float4* __restrict__ part4, const float* __restrict__ consts,
    float* __restrict__ bs)
{
  const int gid = blockIdx.x * 256 + threadIdx.x;    // 0..16383
  const int b = gid >> 11, t = gid & 2047;
  float logit = consts[0];
  #pragma unroll
  for (int hh = 0; hh < NH; ++hh) {
    const size_t p0 = ((size_t)((b * NH + hh) * NT) + t) * 4;   // 4 float4 = 8 {l,sv}
    float lsum = 0.f, ssum = 0.f;
    #pragma unroll
    for (int q = 0; q < 4; ++q) {
      const float4 p = part4[p0 + q];
      lsum += p.x + p.z;
      ssum += p.y + p.w;
    }
    logit += ssum / lsum;
  }
  bs[gid] = 1.f / (1.f + expf(-logit));
}

// ---------------- boundary: cumsum bs, pid, counts (one block per batch) ---------------
__global__ __launch_bounds__(256) void boundary_kernel(
    const float* __restrict__ bs, int* __restrict__ pid, int* __restrict__ counts)
{
  const int b = blockIdx.x, tid = threadIdx.x;
  __shared__ float partial[256];
  __shared__ int cnt_s[8];
  float v[8];
  float run = 0.f;
  const float4 b0 = *(const float4*)(bs + b * NT + tid * 8);
  const float4 b1 = *(const float4*)(bs + b * NT + tid * 8 + 4);
  const float bv[8] = {b0.x, b0.y, b0.z, b0.w, b1.x, b1.y, b1.z, b1.w};
  #pragma unroll
  for (int i = 0; i < 8; ++i) { run += bv[i]; v[i] = run; }
  float x = run;
  partial[tid] = x;
  __syncthreads();
  for (int off = 1; off < 256; off <<= 1) {
    const float y = (tid >= off) ? partial[tid - off] : 0.f;
    __syncthreads();
    x += y;
    partial[tid] = x;
    __syncthreads();
  }
  const float total = partial[255];
  if (tid < 8) cnt_s[tid] = 0;
  __syncthreads();
  const float denom = fmaxf(total, 1e-6f);
  const float excl = x - run;
  #pragma unroll
  for (int i = 0; i < 8; ++i) {
    const float norm = (excl + v[i]) / denom;
    int pp = (int)(norm * 8.f);
    pp = pp > 7 ? 7 : pp;
    pid[b * NT + tid * 8 + i] = pp;
    atomicAdd(&cnt_s[pp], 1);
  }
  __syncthreads();
  if (tid < 8) counts[b * 8 + tid] = cnt_s[tid];
}

// ---------------- pool hhi into patch sums (branchless 8-way select) -------------------
__global__ __launch_bounds__(256) void pool_kernel(
    const unsigned short* __restrict__ hhi, const int* __restrict__ pid,
    float* __restrict__ psum)
{
  const int b = blockIdx.x >> 4, chunk = blockIdx.x & 15;
  const int tid = threadIdx.x;
  __shared__ int pid_s[128];
  const int t0 = chunk * 128;
  if (tid < 128) pid_s[tid] = pid[b * NT + t0 + tid];
  __syncthreads();
  float acc[8] = {};
  for (int tok = 0; tok < 128; ++tok) {
    const float val = bf2f(hhi[((size_t)b * NT + t0 + tok) * NE + tid]);
    const int p = pid_s[tok];
    #pragma unroll
    for (int pp = 0; pp < 8; ++pp) acc[pp] += (p == pp) ? val : 0.f;
  }
  #pragma unroll
  for (int pp = 0; pp < 8; ++pp)
    atomicAdd(&psum[((size_t)b * NP + pp) * NE + tid], acc[pp]);
}

// ---------------- final: out = (psum/count) @ w_pr^T + b_pr ---------------------------
__global__ __launch_bounds__(256) void final_kernel(
    const float* __restrict__ psum, const int* __restrict__ counts,
    const float* __restrict__ w_pr, const float* __restrict__ b_pr, float* __restrict__ out)
{
  const int bp = blockIdx.x;
  const int tid = threadIdx.x;
  __shared__ float pe[NE];
  const float cnt = fmaxf((float)counts[bp], 1.f);
  pe[tid] = psum[(size_t)bp * NE + tid] / cnt;
  __syncthreads();
  float acc = 0.f;
  for (int e = 0; e < NE; ++e) acc = fmaf(pe[e], w_pr[(size_t)tid * NE + e], acc);
  out[(size_t)bp * NE + tid] = acc + b_pr[tid];
}

extern "C" void kernel_launch(void* const* d_in, const int* in_sizes, int n_in,
                              void* d_out, int out_size, void* d_ws, size_t ws_size,
                              hipStream_t stream) {
  (void)in_sizes; (void)n_in; (void)out_size; (void)ws_size;
  const float* x    = (const float*)d_in[0];
  const float* w_in = (const float*)d_in[1];
  const float* b_in = (const float*)d_in[2];
  const float* w_q  = (const float*)d_in[3];
  const float* b_q  = (const float*)d_in[4];
  const float* w_k  = (const float*)d_in[5];
  const float* b_k  = (const float*)d_in[6];
  const float* w_v  = (const float*)d_in[7];
  const float* b_v  = (const float*)d_in[8];
  const float* w_o  = (const float*)d_in[9];
  const float* b_o  = (const float*)d_in[10];
  const float* w_bd = (const float*)d_in[11];
  const float* b_bd = (const float*)d_in[12];
  const float* w_pr = (const float*)d_in[13];
  const float* b_pr = (const float*)d_in[14];
  float* out = (float*)d_out;

  const size_t M = (size_t)NB * NT;                       // 16384
  unsigned short* hhi = (unsigned short*)d_ws;            // M*NE u16
  unsigned short* qhi = hhi + M * NE;
  unsigned short* qlo = qhi + M * NE;
  unsigned short* khi = qlo + M * NE;
  unsigned short* klo = khi + M * NE;
  unsigned short* wfhi = klo + M * NE;                    // 832*256 u16 each
  unsigned short* wflo = wfhi + 212992;
  float* bias_f = (float*)(wflo + 212992);                // 832
  float* uvbuf  = bias_f + 832;                           // 1024
  float* vubuf  = uvbuf + 1024;                           // 65,536 [B,H,T]
  float* part   = vubuf + 65536;                          // 1,048,576 [bh][t][kh8][{l,sv}]
  float* bsbuf  = part + 1048576;                         // 16,384
  float* consts = bsbuf + 16384;                          // 8
  float* psum   = consts + 8;                             // 16,384
  int*   pid    = (int*)(psum + 16384);                   // 16,384
  int*   counts = pid + 16384;                            // 64

  setup1_kernel<<<1, 256, 0, stream>>>(w_o, b_o, w_bd, b_bd, w_v, b_v, uvbuf, consts);
  setup2_kernel<<<98, 256, 0, stream>>>(w_in, w_q, w_k, b_in, b_q, b_k,
      uvbuf, consts, wfhi, wflo, bias_f, psum);
  xgemm_kernel<<<1664, 256, 0, stream>>>(x, wfhi, wflo, bias_f,
      hhi, qhi, qlo, khi, klo, vubuf);
  attn_kernel8<<<2048, 512, 0, stream>>>(qhi, qlo, khi, klo, vubuf, (float2*)part);
  combine_kernel<<<64, 256, 0, stream>>>((const float4*)part, consts, bsbuf);
  boundary_kernel<<<8, 256, 0, stream>>>(bsbuf, pid, counts);
  pool_kernel<<<128, 256, 0, stream>>>(hhi, pid, psum);
  final_kernel<<<64, 256, 0, stream>>>(psum, counts, w_pr, b_pr, out);
}